// Round 7
// baseline (240.410 us; speedup 1.0000x reference)
//
#include <hip/hip_runtime.h>

#define NN 4096
#define NTILE 32          // 128-blocks per dim
#define NLOWER 528        // 32*33/2
#define NUPPER 496
#define NUNITS 1000       // uniform split-K: sum over tiles of ceil((d+1)/8)
#define NSPLIT 300        // tiles with d>=8 (atomic epilogue, pre-zeroed)

typedef __bf16 bf16_t;
typedef __bf16 bf16x8 __attribute__((ext_vector_type(8)));
typedef __bf16 bf16x4 __attribute__((ext_vector_type(4)));
typedef float  f32x4  __attribute__((ext_vector_type(4)));

__device__ inline void gload16(const void* g, void* l) {
    __builtin_amdgcn_global_load_lds(
        (const __attribute__((address_space(1))) void*)g,
        (__attribute__((address_space(3))) void*)l, 16, 0, 0);
}

// ---- compile-time work-unit table, LPT order (chunk size desc).
// Each tile (d+1 = L k-blocks) splits into ceil(L/8) near-equal chunks.
// unit = bi | bj<<8 | k0<<16 | kn<<24 ; k-blocks [k0, k0+kn)
constexpr int count_units() {
    int n = 0;
    for (int d = 0; d < NTILE; ++d) { int L = d + 1; n += (NTILE - d) * ((L + 7) / 8); }
    return n;
}
static_assert(count_units() == NUNITS, "unit count mismatch");

struct UnitTable { unsigned v[NUNITS]; };
constexpr UnitTable make_units() {
    UnitTable t{};
    int n = 0;
    for (int s = 8; s >= 1; --s) {
        for (int d = NTILE - 1; d >= 0; --d) {
            int L = d + 1, nc = (L + 7) / 8;
            int k0 = 0;
            for (int c = 0; c < nc; ++c) {
                int sz = L / nc + (c < L % nc ? 1 : 0);
                if (sz == s)
                    for (int j = 0; j + d < NTILE; ++j)
                        t.v[n++] = (unsigned)((j + d) | (j << 8) | ((j + k0) << 16) | (sz << 24));
                k0 += sz;
            }
        }
    }
    return t;
}
__device__ constexpr UnitTable UNITS = make_units();

// ---- A: f32 -> bf16, lower-triangular 128-blocks, 32-row strips
__global__ __launch_bounds__(256) void conv_a(const float* __restrict__ src,
                                              bf16_t* __restrict__ dst) {
    int id = blockIdx.x >> 2;       // tile 0..527
    int qr = blockIdx.x & 3;        // 32-row quarter
    int rem = id, bi = 0;
    for (;;) { int cnt = bi + 1; if (rem < cnt) break; rem -= cnt; ++bi; }
    int bj = rem;                   // bj <= bi
    int tid = threadIdx.x;
    const float* s = src + (size_t)(bi * 128 + qr * 32) * NN + bj * 128;
    bf16_t*      d = dst + (size_t)(bi * 128 + qr * 32) * NN + bj * 128;
    for (int c = tid; c < 1024; c += 256) {     // 32x128 elems / 4 per chunk
        int row = c >> 5, c4 = c & 31;
        f32x4 v = *(const f32x4*)&s[(size_t)row * NN + c4 * 4];
        bf16x4 o;
        o.x = (bf16_t)v.x; o.y = (bf16_t)v.y; o.z = (bf16_t)v.z; o.w = (bf16_t)v.w;
        *(bf16x4*)&d[(size_t)row * NN + c4 * 4] = o;
    }
}

// ---- B: f32 -> bf16 transpose (Bt[j][k] = B[k][j]); plus tail blocks that
// pre-zero the C tiles which trimm will atomic-add into (d>=8).
__global__ __launch_bounds__(256) void conv_bt(const float* __restrict__ B,
                                               bf16_t* __restrict__ Bt,
                                               float* __restrict__ C) {
    int id = blockIdx.x;
    int tid = threadIdx.x;
    if (id >= 64 * 64) {            // zero a split C tile
        int sid = id - 64 * 64, d = 8;
        for (;;) { int cnt = NTILE - d; if (sid < cnt) break; sid -= cnt; ++d; }
        int bj = sid, bi = sid + d;
        f32x4 z = {0.f, 0.f, 0.f, 0.f};
        float* Cb = C + (size_t)(bi * 128) * NN + bj * 128;
        for (int c = tid; c < 4096; c += 256) {
            int row = c >> 5, c4 = c & 31;
            *(f32x4*)&Cb[(size_t)row * NN + c4 * 4] = z;
        }
        return;
    }
    int jr = id >> 6;               // Bt row 64-block (j)
    int kc = id & 63;               // Bt col 64-block (k)
    if (kc < (jr & ~1)) return;     // never read by GEMM

    __shared__ float tile[64][65];
    const float* s = B + (size_t)(kc * 64) * NN + jr * 64;   // B block (kc, jr)
    for (int q = tid; q < 1024; q += 256) {     // 64x64 / 4
        int row = q >> 4, c4 = q & 15;
        f32x4 v = *(const f32x4*)&s[(size_t)row * NN + c4 * 4];
        tile[row][c4 * 4 + 0] = v.x;
        tile[row][c4 * 4 + 1] = v.y;
        tile[row][c4 * 4 + 2] = v.z;
        tile[row][c4 * 4 + 3] = v.w;
    }
    __syncthreads();
    bf16_t* d = Bt + (size_t)(jr * 64) * NN + kc * 64;
    for (int q = tid; q < 1024; q += 256) {
        int jj = q >> 4, k4 = q & 15;
        bf16x4 o;
        o.x = (bf16_t)tile[k4 * 4 + 0][jj];
        o.y = (bf16_t)tile[k4 * 4 + 1][jj];
        o.z = (bf16_t)tile[k4 * 4 + 2][jj];
        o.w = (bf16_t)tile[k4 * 4 + 3][jj];
        *(bf16x4*)&d[(size_t)jj * NN + k4 * 4] = o;
    }
}

// ---- Triangular GEMM: C = tril(A*B), 128x128 tiles, BK=32, 4 waves, 4x4 frags.
// Work-units from UNITS (LPT order); multi-chunk tiles (d>=8) atomic-add
// into the pre-zeroed C tile.
__global__ __launch_bounds__(256, 2) void trimm(const bf16_t* __restrict__ A,
                                                const bf16_t* __restrict__ Bt,
                                                float* __restrict__ C) {
    __shared__ __align__(16) bf16_t As[4096];   // [128][32]
    __shared__ __align__(16) bf16_t Bs[4096];   // [128][32]  (Bt rows)
    int id = blockIdx.x;
    int tid = threadIdx.x;

    int bi, bj, k0, kn;
    if (id < NUNITS) {
        unsigned u = UNITS.v[id];
        bi = u & 255; bj = (u >> 8) & 255; k0 = (u >> 16) & 255; kn = u >> 24;
    } else {
        // strictly-upper tile: write zeros and exit
        int rem = id - NUNITS, r = 0;
        for (;;) { int cnt = NTILE - 1 - r; if (rem < cnt) { bi = r; bj = r + 1 + rem; break; } rem -= cnt; ++r; }
        f32x4 z = {0.f, 0.f, 0.f, 0.f};
        float* Cb = C + (size_t)(bi * 128) * NN + bj * 128;
        for (int c = tid; c < 4096; c += 256) {
            int row = c >> 5, c4 = c & 31;
            *(f32x4*)&Cb[(size_t)row * NN + c4 * 4] = z;
        }
        return;
    }
    const bool use_atomic = (bi - bj) >= 8;

    int w  = tid >> 6, l = tid & 63;
    int wm = w >> 1,  wn = w & 1;
    int lr = l & 15,  lg = l >> 4;

    f32x4 acc[4][4];
#pragma unroll
    for (int m = 0; m < 4; ++m)
#pragma unroll
        for (int n = 0; n < 4; ++n) acc[m][n] = (f32x4){0.f, 0.f, 0.f, 0.f};

    const bf16_t* Ab = A  + (size_t)(bi * 128) * NN;
    const bf16_t* Bb = Bt + (size_t)(bj * 128) * NN;
    int n0 = w * 64 + l;
    int n1 = n0 + 256;
    const size_t ga0 = (size_t)(n0 >> 2) * NN + (n0 & 3) * 8;   // elem offset
    const size_t ga1 = (size_t)(n1 >> 2) * NN + (n1 & 3) * 8;
    bf16_t* la0 = &As[(w * 64) * 8];
    bf16_t* la1 = &As[(256 + w * 64) * 8];
    bf16_t* lb0 = &Bs[(w * 64) * 8];
    bf16_t* lb1 = &Bs[(256 + w * 64) * 8];

    const int kbeg = k0 * 128, kend = (k0 + kn) * 128;
    for (int k = kbeg; k < kend; k += 32) {
        gload16(Ab + ga0 + k, la0);
        gload16(Ab + ga1 + k, la1);
        gload16(Bb + ga0 + k, lb0);
        gload16(Bb + ga1 + k, lb1);
        __syncthreads();            // compiler drains vmcnt before s_barrier

        bf16x8 af[4], bfr[4];
#pragma unroll
        for (int m = 0; m < 4; ++m)
            af[m] = *(const bf16x8*)&As[(wm * 64 + m * 16 + lr) * 32 + lg * 8];
#pragma unroll
        for (int n = 0; n < 4; ++n)
            bfr[n] = *(const bf16x8*)&Bs[(wn * 64 + n * 16 + lr) * 32 + lg * 8];
#pragma unroll
        for (int m = 0; m < 4; ++m)
#pragma unroll
            for (int n = 0; n < 4; ++n)
                acc[m][n] = __builtin_amdgcn_mfma_f32_16x16x32_bf16(af[m], bfr[n], acc[m][n], 0, 0, 0);
        __syncthreads();
    }

    // epilogue: C/D layout col = lane&15, row = (lane>>4)*4 + reg  [m89-verified]
#pragma unroll
    for (int m = 0; m < 4; ++m) {
        int row0 = bi * 128 + wm * 64 + m * 16 + lg * 4;
#pragma unroll
        for (int n = 0; n < 4; ++n) {
            int col = bj * 128 + wn * 64 + n * 16 + lr;
            f32x4 v = acc[m][n];
            if (use_atomic) {
#pragma unroll
                for (int r = 0; r < 4; ++r)
                    unsafeAtomicAdd(&C[(size_t)(row0 + r) * NN + col], v[r]);
            } else {
#pragma unroll
                for (int r = 0; r < 4; ++r)
                    C[(size_t)(row0 + r) * NN + col] = v[r];
            }
        }
    }
}

extern "C" void kernel_launch(void* const* d_in, const int* in_sizes, int n_in,
                              void* d_out, int out_size, void* d_ws, size_t ws_size,
                              hipStream_t stream) {
    const float* A = (const float*)d_in[0];
    const float* B = (const float*)d_in[1];
    float* C = (float*)d_out;

    bf16_t* Abf = (bf16_t*)d_ws;                                    // 32 MiB
    bf16_t* Btb = (bf16_t*)((char*)d_ws + (size_t)NN * NN * 2);     // 32 MiB

    conv_a <<<NLOWER * 4, 256, 0, stream>>>(A, Abf);
    conv_bt<<<64 * 64 + NSPLIT, 256, 0, stream>>>(B, Btb, C);
    trimm  <<<NUNITS + NUPPER, 256, 0, stream>>>(Abf, Btb, C);
}

// Round 9
// 217.011 us; speedup vs baseline: 1.1078x; 1.1078x over previous
//
#include <hip/hip_runtime.h>

#define NN 4096
#define NTILE 32          // 128-blocks per dim
#define NLOWER 528        // 32*33/2
#define NUPPER 496
#define NUNITS 664        // 528 tiles + 136 extra chunks (d>=16 split in 2)
#define NSPLIT 136        // tiles with d>=16 (atomic epilogue, pre-zeroed)

typedef __bf16 bf16_t;
typedef __bf16 bf16x8 __attribute__((ext_vector_type(8)));
typedef __bf16 bf16x4 __attribute__((ext_vector_type(4)));
typedef float  f32x4  __attribute__((ext_vector_type(4)));

__device__ inline void gload16(const void* g, void* l) {
    __builtin_amdgcn_global_load_lds(
        (const __attribute__((address_space(1))) void*)g,
        (__attribute__((address_space(3))) void*)l, 16, 0, 0);
}

// ---- compile-time work-unit table (round-4 version), LPT order.
// unit = bi | bj<<8 | k0<<16 | kn<<24 ; k-blocks [k0, k0+kn)
struct UnitTable { unsigned v[NUNITS]; };
constexpr UnitTable make_units() {
    UnitTable t{};
    int n = 0;
    for (int s = 16; s >= 1; --s) {
        for (int d = 31; d >= 16; --d) {            // split ceil-chunks
            int c0 = (d + 2) / 2;
            if (c0 == s)
                for (int j = 0; j + d < NTILE; ++j)
                    t.v[n++] = (unsigned)((j + d) | (j << 8) | (j << 16) | (c0 << 24));
        }
        for (int d = 31; d >= 16; --d) {            // split floor-chunks
            int c0 = (d + 2) / 2, c1 = (d + 1) / 2;
            if (c1 == s)
                for (int j = 0; j + d < NTILE; ++j)
                    t.v[n++] = (unsigned)((j + d) | (j << 8) | ((j + c0) << 16) | (c1 << 24));
        }
        for (int d = 15; d >= 0; --d) {             // unsplit tiles
            if (d + 1 == s)
                for (int j = 0; j + d < NTILE; ++j)
                    t.v[n++] = (unsigned)((j + d) | (j << 8) | (j << 16) | ((d + 1) << 24));
        }
    }
    return t;
}
__device__ constexpr UnitTable UNITS = make_units();

// ---- A: f32 -> bf16, lower-triangular 128-blocks, 32-row strips
__global__ __launch_bounds__(256) void conv_a(const float* __restrict__ src,
                                              bf16_t* __restrict__ dst) {
    int id = blockIdx.x >> 2;       // tile 0..527
    int qr = blockIdx.x & 3;        // 32-row quarter
    int rem = id, bi = 0;
    for (;;) { int cnt = bi + 1; if (rem < cnt) break; rem -= cnt; ++bi; }
    int bj = rem;                   // bj <= bi
    int tid = threadIdx.x;
    const float* s = src + (size_t)(bi * 128 + qr * 32) * NN + bj * 128;
    bf16_t*      d = dst + (size_t)(bi * 128 + qr * 32) * NN + bj * 128;
    for (int c = tid; c < 1024; c += 256) {     // 32x128 elems / 4 per chunk
        int row = c >> 5, c4 = c & 31;
        f32x4 v = *(const f32x4*)&s[(size_t)row * NN + c4 * 4];
        bf16x4 o;
        o.x = (bf16_t)v.x; o.y = (bf16_t)v.y; o.z = (bf16_t)v.z; o.w = (bf16_t)v.w;
        *(bf16x4*)&d[(size_t)row * NN + c4 * 4] = o;
    }
}

// ---- B: f32 -> bf16 transpose (Bt[j][k] = B[k][j]); plus tail blocks that
// pre-zero the C tiles which trimm will atomic-add into (d>=16).
__global__ __launch_bounds__(256) void conv_bt(const float* __restrict__ B,
                                               bf16_t* __restrict__ Bt,
                                               float* __restrict__ C) {
    int id = blockIdx.x;
    int tid = threadIdx.x;
    if (id >= 64 * 64) {            // zero a split C tile
        int sid = id - 64 * 64, d = 16;
        for (;;) { int cnt = NTILE - d; if (sid < cnt) break; sid -= cnt; ++d; }
        int bj = sid, bi = sid + d;
        f32x4 z = {0.f, 0.f, 0.f, 0.f};
        float* Cb = C + (size_t)(bi * 128) * NN + bj * 128;
        for (int c = tid; c < 4096; c += 256) {
            int row = c >> 5, c4 = c & 31;
            *(f32x4*)&Cb[(size_t)row * NN + c4 * 4] = z;
        }
        return;
    }
    int jr = id >> 6;               // Bt row 64-block (j)
    int kc = id & 63;               // Bt col 64-block (k)
    if (kc < (jr & ~1)) return;     // never read by GEMM

    __shared__ float tile[64][65];
    const float* s = B + (size_t)(kc * 64) * NN + jr * 64;   // B block (kc, jr)
    for (int q = tid; q < 1024; q += 256) {     // 64x64 / 4
        int row = q >> 4, c4 = q & 15;
        f32x4 v = *(const f32x4*)&s[(size_t)row * NN + c4 * 4];
        tile[row][c4 * 4 + 0] = v.x;
        tile[row][c4 * 4 + 1] = v.y;
        tile[row][c4 * 4 + 2] = v.z;
        tile[row][c4 * 4 + 3] = v.w;
    }
    __syncthreads();
    bf16_t* d = Bt + (size_t)(jr * 64) * NN + kc * 64;
    for (int q = tid; q < 1024; q += 256) {
        int jj = q >> 4, k4 = q & 15;
        bf16x4 o;
        o.x = (bf16_t)tile[k4 * 4 + 0][jj];
        o.y = (bf16_t)tile[k4 * 4 + 1][jj];
        o.z = (bf16_t)tile[k4 * 4 + 2][jj];
        o.w = (bf16_t)tile[k4 * 4 + 3][jj];
        *(bf16x4*)&d[(size_t)jj * NN + k4 * 4] = o;
    }
}

// ---- Triangular GEMM: C = tril(A*B), 128x128 tiles, BK=32, 4 waves, 4x4 frags.
// Double-buffered LDS, prefetch issued BEFORE compute (min-2-phase recipe):
// the __syncthreads() vmcnt(0) drain lands after ds_read+MFMA, so prefetch
// latency hides under the current step's compute. One barrier per K-step.
__global__ __launch_bounds__(256, 4) void trimm(const bf16_t* __restrict__ A,
                                                const bf16_t* __restrict__ Bt,
                                                float* __restrict__ C) {
    __shared__ __align__(16) bf16_t As[2][4096];   // [buf][128][32]
    __shared__ __align__(16) bf16_t Bs[2][4096];   // [buf][128][32]  (Bt rows)
    int id = blockIdx.x;
    int tid = threadIdx.x;

    int bi, bj, k0, kn;
    if (id < NUNITS) {
        unsigned u = UNITS.v[id];
        bi = u & 255; bj = (u >> 8) & 255; k0 = (u >> 16) & 255; kn = u >> 24;
    } else {
        // strictly-upper tile: write zeros and exit
        int rem = id - NUNITS, r = 0;
        for (;;) { int cnt = NTILE - 1 - r; if (rem < cnt) { bi = r; bj = r + 1 + rem; break; } rem -= cnt; ++r; }
        f32x4 z = {0.f, 0.f, 0.f, 0.f};
        float* Cb = C + (size_t)(bi * 128) * NN + bj * 128;
        for (int c = tid; c < 4096; c += 256) {
            int row = c >> 5, c4 = c & 31;
            *(f32x4*)&Cb[(size_t)row * NN + c4 * 4] = z;
        }
        return;
    }
    const bool use_atomic = (bi - bj) >= 16;

    int w  = tid >> 6, l = tid & 63;
    int wm = w >> 1,  wn = w & 1;
    int lr = l & 15,  lg = l >> 4;

    f32x4 acc[4][4];
#pragma unroll
    for (int m = 0; m < 4; ++m)
#pragma unroll
        for (int n = 0; n < 4; ++n) acc[m][n] = (f32x4){0.f, 0.f, 0.f, 0.f};

    const bf16_t* Ab = A  + (size_t)(bi * 128) * NN;
    const bf16_t* Bb = Bt + (size_t)(bj * 128) * NN;
    int n0 = w * 64 + l;
    int n1 = n0 + 256;
    const size_t ga0 = (size_t)(n0 >> 2) * NN + (n0 & 3) * 8;   // elem offset
    const size_t ga1 = (size_t)(n1 >> 2) * NN + (n1 & 3) * 8;
    const int asw = w * 512;        // wave-uniform LDS elem offset (w*64 lanes * 8)

#define STAGE(b, kk) do { \
        gload16(Ab + ga0 + (kk), &As[b][asw]); \
        gload16(Ab + ga1 + (kk), &As[b][asw + 2048]); \
        gload16(Bb + ga0 + (kk), &Bs[b][asw]); \
        gload16(Bb + ga1 + (kk), &Bs[b][asw + 2048]); \
    } while (0)

    const int kbeg = k0 * 128;
    const int nsteps = kn * 4;      // BK=32 steps

    STAGE(0, kbeg);
    __syncthreads();

    int cur = 0;
    for (int t = 0; t < nsteps; ++t) {
        if (t + 1 < nsteps) STAGE(cur ^ 1, kbeg + (t + 1) * 32);

        bf16x8 af[4], bfr[4];
#pragma unroll
        for (int m = 0; m < 4; ++m)
            af[m] = *(const bf16x8*)&As[cur][(wm * 64 + m * 16 + lr) * 32 + lg * 8];
#pragma unroll
        for (int n = 0; n < 4; ++n)
            bfr[n] = *(const bf16x8*)&Bs[cur][(wn * 64 + n * 16 + lr) * 32 + lg * 8];
#pragma unroll
        for (int m = 0; m < 4; ++m)
#pragma unroll
            for (int n = 0; n < 4; ++n)
                acc[m][n] = __builtin_amdgcn_mfma_f32_16x16x32_bf16(af[m], bfr[n], acc[m][n], 0, 0, 0);

        __syncthreads();            // drains prefetch vmcnt + syncs LDS reuse
        cur ^= 1;
    }
#undef STAGE

    // epilogue: C/D layout col = lane&15, row = (lane>>4)*4 + reg  [m89-verified]
#pragma unroll
    for (int m = 0; m < 4; ++m) {
        int row0 = bi * 128 + wm * 64 + m * 16 + lg * 4;
#pragma unroll
        for (int n = 0; n < 4; ++n) {
            int col = bj * 128 + wn * 64 + n * 16 + lr;
            f32x4 v = acc[m][n];
            if (use_atomic) {
#pragma unroll
                for (int r = 0; r < 4; ++r)
                    unsafeAtomicAdd(&C[(size_t)(row0 + r) * NN + col], v[r]);
            } else {
#pragma unroll
                for (int r = 0; r < 4; ++r)
                    C[(size_t)(row0 + r) * NN + col] = v[r];
            }
        }
    }
}

extern "C" void kernel_launch(void* const* d_in, const int* in_sizes, int n_in,
                              void* d_out, int out_size, void* d_ws, size_t ws_size,
                              hipStream_t stream) {
    const float* A = (const float*)d_in[0];
    const float* B = (const float*)d_in[1];
    float* C = (float*)d_out;

    bf16_t* Abf = (bf16_t*)d_ws;                                    // 32 MiB
    bf16_t* Btb = (bf16_t*)((char*)d_ws + (size_t)NN * NN * 2);     // 32 MiB

    conv_a <<<NLOWER * 4, 256, 0, stream>>>(A, Abf);
    conv_bt<<<64 * 64 + NSPLIT, 256, 0, stream>>>(B, Btb, C);
    trimm  <<<NUNITS + NUPPER, 256, 0, stream>>>(Abf, Btb, C);
}

// Round 14
// 211.032 us; speedup vs baseline: 1.1392x; 1.0283x over previous
//
#include <hip/hip_runtime.h>

#define NN 4096
#define NTILE 32          // 128-blocks per dim
#define NLOWER 528        // 32*33/2
#define NUPPER 496
#define NUNITS 664        // 528 tiles + 136 extra chunks (d>=16 split in 2)
#define NSPLIT 136        // tiles with d>=16 (atomic epilogue, pre-zeroed)
#define NXCD 8

typedef __bf16 bf16_t;
typedef __bf16 bf16x8 __attribute__((ext_vector_type(8)));
typedef __bf16 bf16x4 __attribute__((ext_vector_type(4)));
typedef float  f32x4  __attribute__((ext_vector_type(4)));

__device__ inline void gload16(const void* g, void* l) {
    __builtin_amdgcn_global_load_lds(
        (const __attribute__((address_space(1))) void*)g,
        (__attribute__((address_space(3))) void*)l, 16, 0, 0);
}

// ---- compile-time schedule: units grouped by bi-row-band onto 8 XCD queues
// (round-robin dispatch => queue q lands on XCD q), LPT order within queue.
// unit = bi | bj<<8 | k0<<16 | kn<<24 ; k-blocks [k0, k0+kn)
struct Sched { unsigned v[NUNITS]; };
constexpr Sched make_sched() {
    // 1. assign each row bi to the lightest queue (balance sum of row work)
    int rowq[NTILE] = {};
    long load[NXCD] = {};
    for (int bi = NTILE - 1; bi >= 0; --bi) {
        long rl = (long)(bi + 1) * (bi + 2) / 2;    // sum of (d+1) over row
        int best = 0;
        for (int q = 1; q < NXCD; ++q) if (load[q] < load[best]) best = q;
        rowq[bi] = best; load[best] += rl;
    }
    // 2. enumerate units in global LPT (size-desc) order, push to row queues
    unsigned qbuf[NXCD][NUNITS] = {};
    int qlen[NXCD] = {};
    for (int s = 16; s >= 1; --s) {
        for (int d = 31; d >= 16; --d) {            // split ceil-chunks
            int c0 = (d + 2) / 2;
            if (c0 == s)
                for (int j = 0; j + d < NTILE; ++j) {
                    int bi = j + d, q = rowq[bi];
                    qbuf[q][qlen[q]++] = (unsigned)(bi | (j << 8) | (j << 16) | (c0 << 24));
                }
        }
        for (int d = 31; d >= 16; --d) {            // split floor-chunks
            int c0 = (d + 2) / 2, c1 = (d + 1) / 2;
            if (c1 == s)
                for (int j = 0; j + d < NTILE; ++j) {
                    int bi = j + d, q = rowq[bi];
                    qbuf[q][qlen[q]++] = (unsigned)(bi | (j << 8) | ((j + c0) << 16) | (c1 << 24));
                }
        }
        for (int d = 15; d >= 0; --d) {             // unsplit tiles
            if (d + 1 == s)
                for (int j = 0; j + d < NTILE; ++j) {
                    int bi = j + d, q = rowq[bi];
                    qbuf[q][qlen[q]++] = (unsigned)(bi | (j << 8) | (j << 16) | ((d + 1) << 24));
                }
        }
    }
    // 3. interleave queues at stride NXCD (skip exhausted queues in the tail)
    Sched t{};
    int n = 0, pos[NXCD] = {};
    while (n < NUNITS) {
        for (int q = 0; q < NXCD && n < NUNITS; ++q)
            if (pos[q] < qlen[q]) t.v[n++] = qbuf[q][pos[q]++];
    }
    return t;
}
__device__ constexpr Sched UNITS = make_sched();

// ---- A: f32 -> bf16, lower-triangular 128-blocks, 32-row strips
__global__ __launch_bounds__(256) void conv_a(const float* __restrict__ src,
                                              bf16_t* __restrict__ dst) {
    int id = blockIdx.x >> 2;       // tile 0..527
    int qr = blockIdx.x & 3;        // 32-row quarter
    int rem = id, bi = 0;
    for (;;) { int cnt = bi + 1; if (rem < cnt) break; rem -= cnt; ++bi; }
    int bj = rem;                   // bj <= bi
    int tid = threadIdx.x;
    const float* s = src + (size_t)(bi * 128 + qr * 32) * NN + bj * 128;
    bf16_t*      d = dst + (size_t)(bi * 128 + qr * 32) * NN + bj * 128;
    for (int c = tid; c < 1024; c += 256) {     // 32x128 elems / 4 per chunk
        int row = c >> 5, c4 = c & 31;
        f32x4 v = *(const f32x4*)&s[(size_t)row * NN + c4 * 4];
        bf16x4 o;
        o.x = (bf16_t)v.x; o.y = (bf16_t)v.y; o.z = (bf16_t)v.z; o.w = (bf16_t)v.w;
        *(bf16x4*)&d[(size_t)row * NN + c4 * 4] = o;
    }
}

// ---- B: f32 -> bf16 transpose (Bt[j][k] = B[k][j]); plus tail blocks that
// pre-zero the C tiles which trimm will atomic-add into (d>=16).
__global__ __launch_bounds__(256) void conv_bt(const float* __restrict__ B,
                                               bf16_t* __restrict__ Bt,
                                               float* __restrict__ C) {
    int id = blockIdx.x;
    int tid = threadIdx.x;
    if (id >= 64 * 64) {            // zero a split C tile
        int sid = id - 64 * 64, d = 16;
        for (;;) { int cnt = NTILE - d; if (sid < cnt) break; sid -= cnt; ++d; }
        int bj = sid, bi = sid + d;
        f32x4 z = {0.f, 0.f, 0.f, 0.f};
        float* Cb = C + (size_t)(bi * 128) * NN + bj * 128;
        for (int c = tid; c < 4096; c += 256) {
            int row = c >> 5, c4 = c & 31;
            *(f32x4*)&Cb[(size_t)row * NN + c4 * 4] = z;
        }
        return;
    }
    int jr = id >> 6;               // Bt row 64-block (j)
    int kc = id & 63;               // Bt col 64-block (k)
    if (kc < (jr & ~1)) return;     // never read by GEMM

    __shared__ float tile[64][65];
    const float* s = B + (size_t)(kc * 64) * NN + jr * 64;   // B block (kc, jr)
    for (int q = tid; q < 1024; q += 256) {     // 64x64 / 4
        int row = q >> 4, c4 = q & 15;
        f32x4 v = *(const f32x4*)&s[(size_t)row * NN + c4 * 4];
        tile[row][c4 * 4 + 0] = v.x;
        tile[row][c4 * 4 + 1] = v.y;
        tile[row][c4 * 4 + 2] = v.z;
        tile[row][c4 * 4 + 3] = v.w;
    }
    __syncthreads();
    bf16_t* d = Bt + (size_t)(jr * 64) * NN + kc * 64;
    for (int q = tid; q < 1024; q += 256) {
        int jj = q >> 4, k4 = q & 15;
        bf16x4 o;
        o.x = (bf16_t)tile[k4 * 4 + 0][jj];
        o.y = (bf16_t)tile[k4 * 4 + 1][jj];
        o.z = (bf16_t)tile[k4 * 4 + 2][jj];
        o.w = (bf16_t)tile[k4 * 4 + 3][jj];
        *(bf16x4*)&d[(size_t)jj * NN + k4 * 4] = o;
    }
}

// ---- Triangular GEMM: C = tril(A*B), 128x128 tiles, BK=32, 4 waves, 4x4 frags.
// (round-4 body; single-buffered — dbuf measured null at this occupancy)
__global__ __launch_bounds__(256, 2) void trimm(const bf16_t* __restrict__ A,
                                                const bf16_t* __restrict__ Bt,
                                                float* __restrict__ C) {
    __shared__ __align__(16) bf16_t As[4096];   // [128][32]
    __shared__ __align__(16) bf16_t Bs[4096];   // [128][32]  (Bt rows)
    int id = blockIdx.x;
    int tid = threadIdx.x;

    int bi, bj, k0, kn;
    if (id < NUNITS) {
        unsigned u = UNITS.v[id];
        bi = u & 255; bj = (u >> 8) & 255; k0 = (u >> 16) & 255; kn = u >> 24;
    } else {
        // strictly-upper tile: write zeros and exit
        int rem = id - NUNITS, r = 0;
        for (;;) { int cnt = NTILE - 1 - r; if (rem < cnt) { bi = r; bj = r + 1 + rem; break; } rem -= cnt; ++r; }
        f32x4 z = {0.f, 0.f, 0.f, 0.f};
        float* Cb = C + (size_t)(bi * 128) * NN + bj * 128;
        for (int c = tid; c < 4096; c += 256) {
            int row = c >> 5, c4 = c & 31;
            *(f32x4*)&Cb[(size_t)row * NN + c4 * 4] = z;
        }
        return;
    }
    const bool use_atomic = (bi - bj) >= 16;

    int w  = tid >> 6, l = tid & 63;
    int wm = w >> 1,  wn = w & 1;
    int lr = l & 15,  lg = l >> 4;

    f32x4 acc[4][4];
#pragma unroll
    for (int m = 0; m < 4; ++m)
#pragma unroll
        for (int n = 0; n < 4; ++n) acc[m][n] = (f32x4){0.f, 0.f, 0.f, 0.f};

    const bf16_t* Ab = A  + (size_t)(bi * 128) * NN;
    const bf16_t* Bb = Bt + (size_t)(bj * 128) * NN;
    int n0 = w * 64 + l;
    int n1 = n0 + 256;
    const size_t ga0 = (size_t)(n0 >> 2) * NN + (n0 & 3) * 8;   // elem offset
    const size_t ga1 = (size_t)(n1 >> 2) * NN + (n1 & 3) * 8;
    bf16_t* la0 = &As[(w * 64) * 8];
    bf16_t* la1 = &As[(256 + w * 64) * 8];
    bf16_t* lb0 = &Bs[(w * 64) * 8];
    bf16_t* lb1 = &Bs[(256 + w * 64) * 8];

    const int kbeg = k0 * 128, kend = (k0 + kn) * 128;
    for (int k = kbeg; k < kend; k += 32) {
        gload16(Ab + ga0 + k, la0);
        gload16(Ab + ga1 + k, la1);
        gload16(Bb + ga0 + k, lb0);
        gload16(Bb + ga1 + k, lb1);
        __syncthreads();            // compiler drains vmcnt before s_barrier

        bf16x8 af[4], bfr[4];
#pragma unroll
        for (int m = 0; m < 4; ++m)
            af[m] = *(const bf16x8*)&As[(wm * 64 + m * 16 + lr) * 32 + lg * 8];
#pragma unroll
        for (int n = 0; n < 4; ++n)
            bfr[n] = *(const bf16x8*)&Bs[(wn * 64 + n * 16 + lr) * 32 + lg * 8];
#pragma unroll
        for (int m = 0; m < 4; ++m)
#pragma unroll
            for (int n = 0; n < 4; ++n)
                acc[m][n] = __builtin_amdgcn_mfma_f32_16x16x32_bf16(af[m], bfr[n], acc[m][n], 0, 0, 0);
        __syncthreads();
    }

    // epilogue: C/D layout col = lane&15, row = (lane>>4)*4 + reg  [m89-verified]
#pragma unroll
    for (int m = 0; m < 4; ++m) {
        int row0 = bi * 128 + wm * 64 + m * 16 + lg * 4;
#pragma unroll
        for (int n = 0; n < 4; ++n) {
            int col = bj * 128 + wn * 64 + n * 16 + lr;
            f32x4 v = acc[m][n];
            if (use_atomic) {
#pragma unroll
                for (int r = 0; r < 4; ++r)
                    unsafeAtomicAdd(&C[(size_t)(row0 + r) * NN + col], v[r]);
            } else {
#pragma unroll
                for (int r = 0; r < 4; ++r)
                    C[(size_t)(row0 + r) * NN + col] = v[r];
            }
        }
    }
}

extern "C" void kernel_launch(void* const* d_in, const int* in_sizes, int n_in,
                              void* d_out, int out_size, void* d_ws, size_t ws_size,
                              hipStream_t stream) {
    const float* A = (const float*)d_in[0];
    const float* B = (const float*)d_in[1];
    float* C = (float*)d_out;

    bf16_t* Abf = (bf16_t*)d_ws;                                    // 32 MiB
    bf16_t* Btb = (bf16_t*)((char*)d_ws + (size_t)NN * NN * 2);     // 32 MiB

    conv_a <<<NLOWER * 4, 256, 0, stream>>>(A, Abf);
    conv_bt<<<64 * 64 + NSPLIT, 256, 0, stream>>>(B, Btb, C);
    trimm  <<<NUNITS + NUPPER, 256, 0, stream>>>(Abf, Btb, C);
}

// Round 15
// 203.640 us; speedup vs baseline: 1.1806x; 1.0363x over previous
//
#include <hip/hip_runtime.h>

#define NN 4096
#define NTILE 32          // 128-blocks per dim
#define NLOWER 528        // 32*33/2
#define NUPPER 496
#define NUNITS 664        // 528 tiles + 136 extra chunks (d>=16 split in 2)
#define NSPLIT 136        // tiles with d>=16 (atomic epilogue, pre-zeroed)
#define NXCD 8

typedef __bf16 bf16_t;
typedef __bf16 bf16x8 __attribute__((ext_vector_type(8)));
typedef __bf16 bf16x4 __attribute__((ext_vector_type(4)));
typedef float  f32x4  __attribute__((ext_vector_type(4)));

__device__ inline void gload16(const void* g, void* l) {
    __builtin_amdgcn_global_load_lds(
        (const __attribute__((address_space(1))) void*)g,
        (__attribute__((address_space(3))) void*)l, 16, 0, 0);
}

// ---- compile-time schedule: units grouped by bi-row-band onto 8 XCD queues
// (round-robin dispatch => queue q lands on XCD q), LPT order within queue.
// unit = bi | bj<<8 | k0<<16 | kn<<24 ; k-blocks [k0, k0+kn)
struct Sched { unsigned v[NUNITS]; };
constexpr Sched make_sched() {
    int rowq[NTILE] = {};
    long load[NXCD] = {};
    for (int bi = NTILE - 1; bi >= 0; --bi) {
        long rl = (long)(bi + 1) * (bi + 2) / 2;
        int best = 0;
        for (int q = 1; q < NXCD; ++q) if (load[q] < load[best]) best = q;
        rowq[bi] = best; load[best] += rl;
    }
    unsigned qbuf[NXCD][NUNITS] = {};
    int qlen[NXCD] = {};
    for (int s = 16; s >= 1; --s) {
        for (int d = 31; d >= 16; --d) {            // split ceil-chunks
            int c0 = (d + 2) / 2;
            if (c0 == s)
                for (int j = 0; j + d < NTILE; ++j) {
                    int bi = j + d, q = rowq[bi];
                    qbuf[q][qlen[q]++] = (unsigned)(bi | (j << 8) | (j << 16) | (c0 << 24));
                }
        }
        for (int d = 31; d >= 16; --d) {            // split floor-chunks
            int c0 = (d + 2) / 2, c1 = (d + 1) / 2;
            if (c1 == s)
                for (int j = 0; j + d < NTILE; ++j) {
                    int bi = j + d, q = rowq[bi];
                    qbuf[q][qlen[q]++] = (unsigned)(bi | (j << 8) | ((j + c0) << 16) | (c1 << 24));
                }
        }
        for (int d = 15; d >= 0; --d) {             // unsplit tiles
            if (d + 1 == s)
                for (int j = 0; j + d < NTILE; ++j) {
                    int bi = j + d, q = rowq[bi];
                    qbuf[q][qlen[q]++] = (unsigned)(bi | (j << 8) | (j << 16) | ((d + 1) << 24));
                }
        }
    }
    Sched t{};
    int n = 0, pos[NXCD] = {};
    while (n < NUNITS) {
        for (int q = 0; q < NXCD && n < NUNITS; ++q)
            if (pos[q] < qlen[q]) t.v[n++] = qbuf[q][pos[q]++];
    }
    return t;
}
__device__ constexpr Sched UNITS = make_sched();

// ---- A: f32 -> bf16, lower-triangular 128-blocks, 32-row strips
__global__ __launch_bounds__(256) void conv_a(const float* __restrict__ src,
                                              bf16_t* __restrict__ dst) {
    int id = blockIdx.x >> 2;       // tile 0..527
    int qr = blockIdx.x & 3;        // 32-row quarter
    int rem = id, bi = 0;
    for (;;) { int cnt = bi + 1; if (rem < cnt) break; rem -= cnt; ++bi; }
    int bj = rem;                   // bj <= bi
    int tid = threadIdx.x;
    const float* s = src + (size_t)(bi * 128 + qr * 32) * NN + bj * 128;
    bf16_t*      d = dst + (size_t)(bi * 128 + qr * 32) * NN + bj * 128;
    for (int c = tid; c < 1024; c += 256) {
        int row = c >> 5, c4 = c & 31;
        f32x4 v = *(const f32x4*)&s[(size_t)row * NN + c4 * 4];
        bf16x4 o;
        o.x = (bf16_t)v.x; o.y = (bf16_t)v.y; o.z = (bf16_t)v.z; o.w = (bf16_t)v.w;
        *(bf16x4*)&d[(size_t)row * NN + c4 * 4] = o;
    }
}

// ---- B: f32 -> bf16 transpose (Bt[j][k] = B[k][j]); plus tail blocks that
// pre-zero the C tiles which trimm will atomic-add into (d>=16).
__global__ __launch_bounds__(256) void conv_bt(const float* __restrict__ B,
                                               bf16_t* __restrict__ Bt,
                                               float* __restrict__ C) {
    int id = blockIdx.x;
    int tid = threadIdx.x;
    if (id >= 64 * 64) {            // zero a split C tile
        int sid = id - 64 * 64, d = 16;
        for (;;) { int cnt = NTILE - d; if (sid < cnt) break; sid -= cnt; ++d; }
        int bj = sid, bi = sid + d;
        f32x4 z = {0.f, 0.f, 0.f, 0.f};
        float* Cb = C + (size_t)(bi * 128) * NN + bj * 128;
        for (int c = tid; c < 4096; c += 256) {
            int row = c >> 5, c4 = c & 31;
            *(f32x4*)&Cb[(size_t)row * NN + c4 * 4] = z;
        }
        return;
    }
    int jr = id >> 6;               // Bt row 64-block (j)
    int kc = id & 63;               // Bt col 64-block (k)
    if (kc < (jr & ~1)) return;     // never read by GEMM

    __shared__ float tile[64][65];
    const float* s = B + (size_t)(kc * 64) * NN + jr * 64;
    for (int q = tid; q < 1024; q += 256) {
        int row = q >> 4, c4 = q & 15;
        f32x4 v = *(const f32x4*)&s[(size_t)row * NN + c4 * 4];
        tile[row][c4 * 4 + 0] = v.x;
        tile[row][c4 * 4 + 1] = v.y;
        tile[row][c4 * 4 + 2] = v.z;
        tile[row][c4 * 4 + 3] = v.w;
    }
    __syncthreads();
    bf16_t* d = Bt + (size_t)(jr * 64) * NN + kc * 64;
    for (int q = tid; q < 1024; q += 256) {
        int jj = q >> 4, k4 = q & 15;
        bf16x4 o;
        o.x = (bf16_t)tile[k4 * 4 + 0][jj];
        o.y = (bf16_t)tile[k4 * 4 + 1][jj];
        o.z = (bf16_t)tile[k4 * 4 + 2][jj];
        o.w = (bf16_t)tile[k4 * 4 + 3][jj];
        *(bf16x4*)&d[(size_t)jj * NN + k4 * 4] = o;
    }
}

// ---- Triangular GEMM: C = tril(A*B), 128x128 tiles, BK=64, 4 waves, 4x4 frags.
// LDS tiles [128][64] bf16 with st-style XOR swizzle (byte ^= (row&7)<<4),
// applied on BOTH the global-source side (gload_lds writes linearly) and the
// ds_read side — same involution (rule 21). 32 MFMA per 2-barrier step.
__global__ __launch_bounds__(256, 2) void trimm(const bf16_t* __restrict__ A,
                                                const bf16_t* __restrict__ Bt,
                                                float* __restrict__ C) {
    __shared__ __align__(16) bf16_t As[8192];   // [128][64] swizzled
    __shared__ __align__(16) bf16_t Bs[8192];   // [128][64] swizzled
    int id = blockIdx.x;
    int tid = threadIdx.x;

    int bi, bj, k0, kn;
    if (id < NUNITS) {
        unsigned u = UNITS.v[id];
        bi = u & 255; bj = (u >> 8) & 255; k0 = (u >> 16) & 255; kn = u >> 24;
    } else {
        // strictly-upper tile: write zeros and exit
        int rem = id - NUNITS, r = 0;
        for (;;) { int cnt = NTILE - 1 - r; if (rem < cnt) { bi = r; bj = r + 1 + rem; break; } rem -= cnt; ++r; }
        f32x4 z = {0.f, 0.f, 0.f, 0.f};
        float* Cb = C + (size_t)(bi * 128) * NN + bj * 128;
        for (int c = tid; c < 4096; c += 256) {
            int row = c >> 5, c4 = c & 31;
            *(f32x4*)&Cb[(size_t)row * NN + c4 * 4] = z;
        }
        return;
    }
    const bool use_atomic = (bi - bj) >= 16;

    int w  = tid >> 6, l = tid & 63;
    int wm = w >> 1,  wn = w & 1;
    int lr = l & 15,  lg = l >> 4;

    f32x4 acc[4][4];
#pragma unroll
    for (int m = 0; m < 4; ++m)
#pragma unroll
        for (int n = 0; n < 4; ++n) acc[m][n] = (f32x4){0.f, 0.f, 0.f, 0.f};

    const bf16_t* Ab = A  + (size_t)(bi * 128) * NN;
    const bf16_t* Bb = Bt + (size_t)(bj * 128) * NN;

    // staging: chunk m = c*256+tid covers LDS bytes [m*16, m*16+16) (linear);
    // that position holds (swizzled) row = m>>3, col16 = (m&7)^(row&7).
    size_t gsw[4];
#pragma unroll
    for (int c = 0; c < 4; ++c) {
        int m = c * 256 + tid;
        int row = m >> 3;
        int c16 = (m & 7) ^ (row & 7);
        gsw[c] = (size_t)row * NN + c16 * 8;
    }

    // fragment read offsets (elem index into swizzled [128][64] tile):
    // unswz (row, 16B-chunk x = t*4+lg) -> elem = row*64 + ((x^(row&7))*8)
    int arow = wm * 64 + lr;        // + m_*16
    int brow = wn * 64 + lr;        // + n_*16

    const int kbeg = k0 * 128, kend = (k0 + kn) * 128;
    for (int k = kbeg; k < kend; k += 64) {
#pragma unroll
        for (int c = 0; c < 4; ++c) {
            int m = c * 256 + tid;
            gload16(Ab + gsw[c] + k, &As[m * 8]);
            gload16(Bb + gsw[c] + k, &Bs[m * 8]);
        }
        __syncthreads();            // compiler drains vmcnt before s_barrier

#pragma unroll
        for (int t = 0; t < 2; ++t) {
            bf16x8 af[4], bfr[4];
#pragma unroll
            for (int m_ = 0; m_ < 4; ++m_) {
                int row = arow + m_ * 16;
                af[m_] = *(const bf16x8*)&As[row * 64 + (((t * 4 + lg) ^ (row & 7)) * 8)];
            }
#pragma unroll
            for (int n_ = 0; n_ < 4; ++n_) {
                int row = brow + n_ * 16;
                bfr[n_] = *(const bf16x8*)&Bs[row * 64 + (((t * 4 + lg) ^ (row & 7)) * 8)];
            }
#pragma unroll
            for (int m_ = 0; m_ < 4; ++m_)
#pragma unroll
                for (int n_ = 0; n_ < 4; ++n_)
                    acc[m_][n_] = __builtin_amdgcn_mfma_f32_16x16x32_bf16(af[m_], bfr[n_], acc[m_][n_], 0, 0, 0);
        }
        __syncthreads();
    }

    // epilogue: C/D layout col = lane&15, row = (lane>>4)*4 + reg  [m89-verified]
#pragma unroll
    for (int m = 0; m < 4; ++m) {
        int row0 = bi * 128 + wm * 64 + m * 16 + lg * 4;
#pragma unroll
        for (int n = 0; n < 4; ++n) {
            int col = bj * 128 + wn * 64 + n * 16 + lr;
            f32x4 v = acc[m][n];
            if (use_atomic) {
#pragma unroll
                for (int r = 0; r < 4; ++r)
                    unsafeAtomicAdd(&C[(size_t)(row0 + r) * NN + col], v[r]);
            } else {
#pragma unroll
                for (int r = 0; r < 4; ++r)
                    C[(size_t)(row0 + r) * NN + col] = v[r];
            }
        }
    }
}

extern "C" void kernel_launch(void* const* d_in, const int* in_sizes, int n_in,
                              void* d_out, int out_size, void* d_ws, size_t ws_size,
                              hipStream_t stream) {
    const float* A = (const float*)d_in[0];
    const float* B = (const float*)d_in[1];
    float* C = (float*)d_out;

    bf16_t* Abf = (bf16_t*)d_ws;                                    // 32 MiB
    bf16_t* Btb = (bf16_t*)((char*)d_ws + (size_t)NN * NN * 2);     // 32 MiB

    conv_a <<<NLOWER * 4, 256, 0, stream>>>(A, Abf);
    conv_bt<<<64 * 64 + NSPLIT, 256, 0, stream>>>(B, Btb, C);
    trimm  <<<NUNITS + NUPPER, 256, 0, stream>>>(Abf, Btb, C);
}